// Round 10
// baseline (351.550 us; speedup 1.0000x reference)
//
#include <hip/hip_runtime.h>

// Legendre2 via split-precision MFMA, v10: latency-targeted fixes on the R2
// structure. Full A-table (96 KB) + C (8 KB) + scratch (16 KB) in LDS; no
// main-loop barriers. Per level: 16 ds_read_b128 -> 16 independent 3-deep
// MFMA chains (split k-half accumulators a0/a1) -> fold. s_setprio(1) wraps
// each level's MFMA cluster (T5: waves are phase-staggered, not lockstep).
// Next-iter z loads issue BEFORE the epilogue so its ~1.5k cyc of compute
// covers HBM latency (T14).
// W_i = Z @ A_i^T as f16 hi/lo 3-term MFMA (f32 accum), elementwise Legendre
// fold in f32 regs, epilogue P6 @ C^T + beta as bf16 hi/lo 3-term MFMA.
// N=524288, D=64, K=64, O=32, DEGREE=6.

typedef _Float16 f16x8 __attribute__((ext_vector_type(8)));
typedef short    s16x8 __attribute__((ext_vector_type(8)));
typedef float    f32x4 __attribute__((ext_vector_type(4)));

#define NN      524288
#define BLOCKS  256
#define THREADS 512
#define NWAVES  8
#define ROWS_PER_WAVE 256               // 256 blocks * 8 waves * 256 = N
#define NITER   8                       // 8 x 32-row tiles per wave

// d_ws byte layout (prep output): level L at L*16384 = [hi 8KB][lo 8KB]
#define WS_CF   98304                   // 8 frags * 1 KB (bf16 h/l of C)
#define WS_TOTAL 106496

// main-kernel LDS byte offsets
#define A_OFF   0                       // 96 KB (6 levels)
#define CF_OFF  98304                   // 8 KB
#define SCR_OFF 106496                  // 8 waves * 2 KB transpose scratch
#define SMEM_BYTES (SCR_OFF + NWAVES * 2048)   // 122880 B

__device__ __forceinline__ unsigned short f2bf(float x) {
    unsigned u = __builtin_bit_cast(unsigned, x);
    return (unsigned short)((u + 0x7FFFu + ((u >> 16) & 1u)) >> 16);
}

// ---------------------------------------------------------------------------
// prep: build fragment tables in d_ws (unchanged from v8/v9)
// ---------------------------------------------------------------------------
__global__ __launch_bounds__(512) void leg_prep(
    const float* __restrict__ T, const float* __restrict__ Cm,
    char* __restrict__ ws)
{
    __shared__ float scale_s[384];
    const int tid = (int)threadIdx.x;

    if (tid < 384) {
        const int mat = tid >> 6, kc = tid & 63;
        const float4* tr = (const float4*)(T + (size_t)((mat << 6) + kc) * 64);
        float s = 0.f;
        #pragma unroll
        for (int q = 0; q < 16; ++q) { float4 v = tr[q]; s += v.x + v.y + v.z + v.w; }
        float sc;
        if (mat == 0) sc = 1.f;
        else { const float fi = (float)(mat + 1); sc = (2.f * fi - 1.f) / fi / s; }
        scale_s[tid] = sc;
    }
    __syncthreads();

    // A fragments: level `mat`, frag(s,f): lane l supplies
    // A[col=(l&15)+16f][32s+(l>>4)*8+j] * scale, j=0..7.
    for (int g = tid; g < 3072; g += 512) {
        const int mat = g >> 9;
        const int s   = (g >> 8) & 1;
        const int f   = (g >> 6) & 3;
        const int l   = g & 63;
        const int kc  = (l & 15) + (f << 4);
        const int d0  = ((l >> 4) << 3) + (s << 5);
        const float sc = scale_s[(mat << 6) + kc];
        const float* src = T + (size_t)((mat << 6) + kc) * 64 + d0;
        const float4 v0 = *(const float4*)(src);
        const float4 v1 = *(const float4*)(src + 4);
        const float vv[8] = {v0.x, v0.y, v0.z, v0.w, v1.x, v1.y, v1.z, v1.w};
        f16x8 hi, lo;
        #pragma unroll
        for (int j = 0; j < 8; ++j) {
            const float x = vv[j] * sc;
            const _Float16 h = (_Float16)x;
            hi[j] = h;
            lo[j] = (_Float16)(x - (float)h);
        }
        char* lvlbase = ws + mat * 16384;
        const int fr = (s << 2) + f;                   // 0..7 within level
        *(f16x8*)(lvlbase + fr * 1024 + l * 16) = hi;
        *(f16x8*)(lvlbase + 8192 + fr * 1024 + l * 16) = lo;
    }

    // C fragments (bf16 hi/lo): frag(hl,s,fo), lane l supplies
    // C2[k=32s+(l>>4)*8+j][o=(l&15)+16fo] = C[o][k].
    {
        const int hl = (tid >> 8) & 1;
        const int s  = (tid >> 7) & 1;
        const int fo = (tid >> 6) & 1;
        const int l  = tid & 63;
        const int o  = (l & 15) + (fo << 4);
        const int k0 = ((l >> 4) << 3) + (s << 5);
        const float* src = Cm + (size_t)o * 64 + k0;
        const float4 v0 = *(const float4*)src;
        const float4 v1 = *(const float4*)(src + 4);
        const float vv[8] = {v0.x, v0.y, v0.z, v0.w, v1.x, v1.y, v1.z, v1.w};
        s16x8 fr;
        #pragma unroll
        for (int j = 0; j < 8; ++j) {
            const float x = vv[j];
            const unsigned short h = f2bf(x);
            if (hl) {
                const float hf = __builtin_bit_cast(float, (unsigned)h << 16);
                fr[j] = (short)f2bf(x - hf);
            } else {
                fr[j] = (short)h;
            }
        }
        *(s16x8*)(ws + WS_CF + ((((hl << 1) + s) << 1) + fo) * 1024 + l * 16) = fr;
    }
}

// ---------------------------------------------------------------------------
// main
// ---------------------------------------------------------------------------
__global__ __launch_bounds__(THREADS)
__attribute__((amdgpu_waves_per_eu(2)))
void leg_mfma(
    const float* __restrict__ z, const char* __restrict__ ws,
    const float* __restrict__ beta, float* __restrict__ out)
{
    extern __shared__ char smem[];
    const int tid  = (int)threadIdx.x;
    const int lane = tid & 63;
    const int wv   = tid >> 6;
    const int lrow = lane & 15;          // row (A-op) / col (C/D) index
    const int lhi  = lane >> 4;          // 0..3

    // stage A levels + C: one linear 104 KB copy (ws layout matches LDS)
    for (int i = tid; i < WS_TOTAL / 16; i += THREADS)
        *(f16x8*)(smem + i * 16) = *(const f16x8*)(ws + i * 16);
    __syncthreads();

    const int    gw      = blockIdx.x * NWAVES + wv;
    const size_t rowbase = (size_t)gw * ROWS_PER_WAVE;
    float* scr = (float*)(smem + SCR_OFF) + wv * 512;  // 16 rows x 32 f32

    const float beta0 = beta[lrow];
    const float beta1 = beta[16 + lrow];

    f16x8 zh[2][2], zl[2][2];
    float4 zraw[2][4];

    auto issue_z = [&](int it) {
        #pragma unroll
        for (int t = 0; t < 2; ++t)
            #pragma unroll
            for (int s = 0; s < 2; ++s) {
                const float* p = z + (rowbase + (size_t)it * 32 + t * 16 + lrow) * 64
                                   + (s << 5) + (lhi << 3);
                zraw[t][2 * s]     = *(const float4*)(p);
                zraw[t][2 * s + 1] = *(const float4*)(p + 4);
            }
    };
    auto convert_z = [&]() {
        #pragma unroll
        for (int t = 0; t < 2; ++t)
            #pragma unroll
            for (int s = 0; s < 2; ++s) {
                const float4 q0 = zraw[t][2 * s], q1 = zraw[t][2 * s + 1];
                const float vv[8] = {q0.x, q0.y, q0.z, q0.w, q1.x, q1.y, q1.z, q1.w};
                #pragma unroll
                for (int j = 0; j < 8; ++j) {
                    const _Float16 h = (_Float16)vv[j];
                    zh[t][s][j] = h;
                    zl[t][s][j] = (_Float16)(vv[j] - (float)h);
                }
            }
    };

    // one Legendre level: PT := (a0 + a1) * PC - b * PT, where a0/a1 are
    // INDEPENDENT k-half chains (depth 3 each) -> 16 chains/level.
    auto leg_level = [&](int lvl, float b, f32x4 (&PC)[2][4], f32x4 (&PT)[2][4]) {
        const char* buf = smem + A_OFF + lvl * 16384;
        __builtin_amdgcn_s_setprio(1);
        #pragma unroll
        for (int f = 0; f < 4; ++f) {
            const f16x8 bh0 = *(const f16x8*)(buf + f * 1024 + lane * 16);
            const f16x8 bl0 = *(const f16x8*)(buf + 8192 + f * 1024 + lane * 16);
            const f16x8 bh1 = *(const f16x8*)(buf + (4 + f) * 1024 + lane * 16);
            const f16x8 bl1 = *(const f16x8*)(buf + 8192 + (4 + f) * 1024 + lane * 16);
            #pragma unroll
            for (int t = 0; t < 2; ++t) {
                f32x4 a0 = {0.f, 0.f, 0.f, 0.f};
                f32x4 a1 = {0.f, 0.f, 0.f, 0.f};
                a0 = __builtin_amdgcn_mfma_f32_16x16x32_f16(zh[t][0], bh0, a0, 0, 0, 0);
                a1 = __builtin_amdgcn_mfma_f32_16x16x32_f16(zh[t][1], bh1, a1, 0, 0, 0);
                a0 = __builtin_amdgcn_mfma_f32_16x16x32_f16(zl[t][0], bh0, a0, 0, 0, 0);
                a1 = __builtin_amdgcn_mfma_f32_16x16x32_f16(zl[t][1], bh1, a1, 0, 0, 0);
                a0 = __builtin_amdgcn_mfma_f32_16x16x32_f16(zh[t][0], bl0, a0, 0, 0, 0);
                a1 = __builtin_amdgcn_mfma_f32_16x16x32_f16(zh[t][1], bl1, a1, 0, 0, 0);
                #pragma unroll
                for (int r = 0; r < 4; ++r)
                    PT[t][f][r] = (a0[r] + a1[r]) * PC[t][f][r] - b * PT[t][f][r];
            }
        }
        __builtin_amdgcn_s_setprio(0);
    };

    issue_z(0);                          // prologue z load

    for (int it = 0; it < NITER; ++it) {
        convert_z();

        f32x4 pA[2][4], pB[2][4];
        // level 0 -> pA (P1): pA = a0 + a1
        {
            const char* buf = smem + A_OFF;
            __builtin_amdgcn_s_setprio(1);
            #pragma unroll
            for (int f = 0; f < 4; ++f) {
                const f16x8 bh0 = *(const f16x8*)(buf + f * 1024 + lane * 16);
                const f16x8 bl0 = *(const f16x8*)(buf + 8192 + f * 1024 + lane * 16);
                const f16x8 bh1 = *(const f16x8*)(buf + (4 + f) * 1024 + lane * 16);
                const f16x8 bl1 = *(const f16x8*)(buf + 8192 + (4 + f) * 1024 + lane * 16);
                #pragma unroll
                for (int t = 0; t < 2; ++t) {
                    f32x4 a0 = {0.f, 0.f, 0.f, 0.f};
                    f32x4 a1 = {0.f, 0.f, 0.f, 0.f};
                    a0 = __builtin_amdgcn_mfma_f32_16x16x32_f16(zh[t][0], bh0, a0, 0, 0, 0);
                    a1 = __builtin_amdgcn_mfma_f32_16x16x32_f16(zh[t][1], bh1, a1, 0, 0, 0);
                    a0 = __builtin_amdgcn_mfma_f32_16x16x32_f16(zl[t][0], bh0, a0, 0, 0, 0);
                    a1 = __builtin_amdgcn_mfma_f32_16x16x32_f16(zl[t][1], bh1, a1, 0, 0, 0);
                    a0 = __builtin_amdgcn_mfma_f32_16x16x32_f16(zh[t][0], bl0, a0, 0, 0, 0);
                    a1 = __builtin_amdgcn_mfma_f32_16x16x32_f16(zh[t][1], bl1, a1, 0, 0, 0);
                    #pragma unroll
                    for (int r = 0; r < 4; ++r)
                        pA[t][f][r] = a0[r] + a1[r];
                }
            }
            __builtin_amdgcn_s_setprio(0);
        }
        // level 1 -> pB = W2*pA - 0.5 (P2; P0 = ones)
        {
            const char* buf = smem + A_OFF + 16384;
            __builtin_amdgcn_s_setprio(1);
            #pragma unroll
            for (int f = 0; f < 4; ++f) {
                const f16x8 bh0 = *(const f16x8*)(buf + f * 1024 + lane * 16);
                const f16x8 bl0 = *(const f16x8*)(buf + 8192 + f * 1024 + lane * 16);
                const f16x8 bh1 = *(const f16x8*)(buf + (4 + f) * 1024 + lane * 16);
                const f16x8 bl1 = *(const f16x8*)(buf + 8192 + (4 + f) * 1024 + lane * 16);
                #pragma unroll
                for (int t = 0; t < 2; ++t) {
                    f32x4 a0 = {0.f, 0.f, 0.f, 0.f};
                    f32x4 a1 = {0.f, 0.f, 0.f, 0.f};
                    a0 = __builtin_amdgcn_mfma_f32_16x16x32_f16(zh[t][0], bh0, a0, 0, 0, 0);
                    a1 = __builtin_amdgcn_mfma_f32_16x16x32_f16(zh[t][1], bh1, a1, 0, 0, 0);
                    a0 = __builtin_amdgcn_mfma_f32_16x16x32_f16(zl[t][0], bh0, a0, 0, 0, 0);
                    a1 = __builtin_amdgcn_mfma_f32_16x16x32_f16(zl[t][1], bh1, a1, 0, 0, 0);
                    a0 = __builtin_amdgcn_mfma_f32_16x16x32_f16(zh[t][0], bl0, a0, 0, 0, 0);
                    a1 = __builtin_amdgcn_mfma_f32_16x16x32_f16(zh[t][1], bl1, a1, 0, 0, 0);
                    #pragma unroll
                    for (int r = 0; r < 4; ++r)
                        pB[t][f][r] = (a0[r] + a1[r]) * pA[t][f][r] - 0.5f;
                }
            }
            __builtin_amdgcn_s_setprio(0);
        }
        leg_level(2, 2.f / 3.f, pB, pA);   // P3
        leg_level(3, 3.f / 4.f, pA, pB);   // P4
        leg_level(4, 4.f / 5.f, pB, pA);   // P5
        leg_level(5, 5.f / 6.f, pA, pB);   // P6 = pB

        // issue next iter's z NOW: the epilogue's ~1.5k cycles cover HBM latency
        if (it + 1 < NITER) issue_z(it + 1);

        // ---------------- epilogue: out = P6 @ C^T + beta --------------------
        #pragma unroll
        for (int t = 0; t < 2; ++t) {
            // transpose P6 (C/D layout) -> A-op layout, two k-32 phases through
            // a 16x32 XOR-swizzled per-wave scratch
            s16x8 p6h[2], p6l[2];
            #pragma unroll
            for (int s = 0; s < 2; ++s) {
                #pragma unroll
                for (int f_ = 0; f_ < 2; ++f_) {
                    const int f    = 2 * s + f_;
                    const int colp = (f_ << 4) + lrow;
                    #pragma unroll
                    for (int r = 0; r < 4; ++r) {
                        const int row = lhi * 4 + r;
                        const int g4  = ((colp >> 2) ^ row) & 7;
                        scr[row * 32 + g4 * 4 + (colp & 3)] = pB[t][f][r];
                    }
                }
                float vv[8];
                #pragma unroll
                for (int jg = 0; jg < 2; ++jg) {
                    const int g4r = (((lhi << 1) + jg) ^ lrow) & 7;
                    const float4 q = *(const float4*)(scr + lrow * 32 + g4r * 4);
                    vv[jg * 4 + 0] = q.x; vv[jg * 4 + 1] = q.y;
                    vv[jg * 4 + 2] = q.z; vv[jg * 4 + 3] = q.w;
                }
                #pragma unroll
                for (int j = 0; j < 8; ++j) {
                    const unsigned short h = f2bf(vv[j]);
                    const float hf = __builtin_bit_cast(float, (unsigned)h << 16);
                    p6h[s][j] = (short)h;
                    p6l[s][j] = (short)f2bf(vv[j] - hf);
                }
            }
            #pragma unroll
            for (int fo = 0; fo < 2; ++fo) {
                const s16x8 ch0 = *(const s16x8*)(smem + CF_OFF + ((0 << 1) + fo) * 1024 + lane * 16);
                const s16x8 ch1 = *(const s16x8*)(smem + CF_OFF + ((1 << 1) + fo) * 1024 + lane * 16);
                const s16x8 cl0 = *(const s16x8*)(smem + CF_OFF + ((2 << 1) + fo) * 1024 + lane * 16);
                const s16x8 cl1 = *(const s16x8*)(smem + CF_OFF + ((3 << 1) + fo) * 1024 + lane * 16);
                f32x4 o = {0.f, 0.f, 0.f, 0.f};
                o = __builtin_amdgcn_mfma_f32_16x16x32_bf16(p6h[0], ch0, o, 0, 0, 0);
                o = __builtin_amdgcn_mfma_f32_16x16x32_bf16(p6l[0], ch0, o, 0, 0, 0);
                o = __builtin_amdgcn_mfma_f32_16x16x32_bf16(p6h[0], cl0, o, 0, 0, 0);
                o = __builtin_amdgcn_mfma_f32_16x16x32_bf16(p6h[1], ch1, o, 0, 0, 0);
                o = __builtin_amdgcn_mfma_f32_16x16x32_bf16(p6l[1], ch1, o, 0, 0, 0);
                o = __builtin_amdgcn_mfma_f32_16x16x32_bf16(p6h[1], cl1, o, 0, 0, 0);
                const float bb = fo ? beta1 : beta0;
                const size_t r0 = rowbase + (size_t)it * 32 + t * 16 + lhi * 4;
                #pragma unroll
                for (int r = 0; r < 4; ++r)
                    out[(r0 + r) * 32 + (fo << 4) + lrow] = o[r] + bb;
            }
        }
    }
}

extern "C" void kernel_launch(void* const* d_in, const int* in_sizes, int n_in,
                              void* d_out, int out_size, void* d_ws, size_t ws_size,
                              hipStream_t stream) {
    const float* z    = (const float*)d_in[0];
    const float* T    = (const float*)d_in[1];
    const float* C    = (const float*)d_in[2];
    const float* beta = (const float*)d_in[3];
    float* out = (float*)d_out;
    (void)in_sizes; (void)n_in; (void)out_size; (void)ws_size;

    char* ws = (char*)d_ws;              // needs WS_TOTAL = 104 KB

    leg_prep<<<1, 512, 0, stream>>>(T, C, ws);

    hipFuncSetAttribute((const void*)leg_mfma,
                        hipFuncAttributeMaxDynamicSharedMemorySize, SMEM_BYTES);
    leg_mfma<<<BLOCKS, THREADS, SMEM_BYTES, stream>>>(z, ws, beta, out);
}

// Round 11
// 86.555 us; speedup vs baseline: 4.0616x; 4.0616x over previous
//
#include <hip/hip_runtime.h>

// Legendre2 via split-precision MFMA, v11: R2 base (91 us, no spills) + TWO
// register-neutral latency fixes, applied alone after v10's spill disaster:
//   (1) a0/a1 k-half split: 16 independent 3-deep MFMA chains per level
//       (was 8 x 6-deep) -- attacks dependent-MFMA latency.
//   (2) s_setprio(1) around each level's MFMA cluster (T5; waves here are
//       barrier-free + phase-drifted, the regime where setprio pays).
// Everything else byte-identical to R2: 512 thr / 8 waves / 256-row waves,
// full A-table (96 KB) + C (8 KB) + 2 KB/wave scratch in LDS, z prefetched
// before the mat chain (NOT across the epilogue -- v10's spill cause).
// N=524288, D=64, K=64, O=32, DEGREE=6.

typedef _Float16 f16x8 __attribute__((ext_vector_type(8)));
typedef short    s16x8 __attribute__((ext_vector_type(8)));
typedef float    f32x4 __attribute__((ext_vector_type(4)));

#define NN      524288
#define BLOCKS  256
#define THREADS 512
#define NWAVES  8

// LDS byte offsets
#define BH_OFF    0                      // 48 frags * 1 KB (f16 hi of A)
#define BL_OFF    49152                  // 48 frags * 1 KB (f16 lo of A)
#define CF_OFF    98304                  // 8 frags * 1 KB (bf16 h/l of C)
#define SCALE_OFF 106496                 // 384 f32 scales
#define SCR_OFF   108032                 // 8 waves * 4 KB transpose scratch
#define SMEM_BYTES (SCR_OFF + NWAVES * 4096)   // 140800 B

__device__ __forceinline__ unsigned short f2bf(float x) {
    unsigned u = __builtin_bit_cast(unsigned, x);
    return (unsigned short)((u + 0x7FFFu + ((u >> 16) & 1u)) >> 16);
}

__global__ __launch_bounds__(THREADS) void leg_mfma(
    const float* __restrict__ z, const float* __restrict__ T,
    const float* __restrict__ Cm, const float* __restrict__ beta,
    float* __restrict__ out)
{
    extern __shared__ char smem[];
    float* scale_s = (float*)(smem + SCALE_OFF);
    const int tid  = (int)threadIdx.x;
    const int lane = tid & 63;
    const int wv   = tid >> 6;
    const int lrow = lane & 15;          // row (A-op) / col (C/D) index
    const int lhi  = lane >> 4;          // 0..3

    // ---------- phase A: per-row scales: j==0 -> 1, else coef_j / rowsum ----
    if (tid < 384) {
        const int mat = tid >> 6, kc = tid & 63;
        const float4* tr = (const float4*)(T + (size_t)((mat << 6) + kc) * 64);
        float s = 0.f;
        #pragma unroll
        for (int q = 0; q < 16; ++q) { float4 v = tr[q]; s += v.x + v.y + v.z + v.w; }
        float sc;
        if (mat == 0) sc = 1.f;
        else { const float fi = (float)(mat + 1); sc = (2.f * fi - 1.f) / fi / s; }
        scale_s[tid] = sc;
    }
    __syncthreads();

    // ---------- phase B: build B-operand frags of A (f16 hi/lo) -------------
    for (int g = tid; g < 3072; g += THREADS) {
        const int mat = g >> 9;
        const int s   = (g >> 8) & 1;
        const int f   = (g >> 6) & 3;
        const int l   = g & 63;
        const int kc  = (l & 15) + (f << 4);
        const int d0  = ((l >> 4) << 3) + (s << 5);
        const float sc = scale_s[(mat << 6) + kc];
        const float* src = T + (size_t)((mat << 6) + kc) * 64 + d0;
        const float4 v0 = *(const float4*)(src);
        const float4 v1 = *(const float4*)(src + 4);
        const float vv[8] = {v0.x, v0.y, v0.z, v0.w, v1.x, v1.y, v1.z, v1.w};
        f16x8 hi, lo;
        #pragma unroll
        for (int j = 0; j < 8; ++j) {
            const float x = vv[j] * sc;
            const _Float16 h = (_Float16)x;
            hi[j] = h;
            lo[j] = (_Float16)(x - (float)h);
        }
        const int fr = (((mat << 1) + s) << 2) + f;
        *(f16x8*)(smem + BH_OFF + fr * 1024 + l * 16) = hi;
        *(f16x8*)(smem + BL_OFF + fr * 1024 + l * 16) = lo;
    }
    // C-operand frags (bf16 hi/lo)
    {
        const int hl = (tid >> 8) & 1;
        const int s  = (tid >> 7) & 1;
        const int fo = (tid >> 6) & 1;
        const int l  = tid & 63;
        const int o  = (l & 15) + (fo << 4);
        const int k0 = ((l >> 4) << 3) + (s << 5);
        const float* src = Cm + (size_t)o * 64 + k0;
        const float4 v0 = *(const float4*)src;
        const float4 v1 = *(const float4*)(src + 4);
        const float vv[8] = {v0.x, v0.y, v0.z, v0.w, v1.x, v1.y, v1.z, v1.w};
        s16x8 fr;
        #pragma unroll
        for (int j = 0; j < 8; ++j) {
            const float x = vv[j];
            const unsigned short h = f2bf(x);
            if (hl) {
                const float hf = __builtin_bit_cast(float, (unsigned)h << 16);
                fr[j] = (short)f2bf(x - hf);
            } else {
                fr[j] = (short)h;
            }
        }
        *(s16x8*)(smem + CF_OFF + ((((hl << 1) + s) << 1) + fo) * 1024 + l * 16) = fr;
    }
    __syncthreads();

    // ---------- main: each wave owns 256 rows, 8 iters of 32 rows -----------
    const int    gw      = blockIdx.x * NWAVES + wv;
    const size_t rowbase = (size_t)gw * 256;
    float* scr = (float*)(smem + SCR_OFF + wv * 4096);

    const float beta0 = beta[lrow];
    const float beta1 = beta[16 + lrow];

    f16x8 zh[2][2], zl[2][2];

    // one Legendre level: PT := (a0+a1) * PC - b * PT; a0/a1 are independent
    // k-half chains of depth 3 (16 chains/level total).
    auto leg_step = [&](int mat, float b, f32x4 (&PC)[2][4], f32x4 (&PT)[2][4]) {
        __builtin_amdgcn_s_setprio(1);
        #pragma unroll
        for (int f = 0; f < 4; ++f) {
            const int fr0 = mat * 8 + f;       // s=0
            const int fr1 = mat * 8 + 4 + f;   // s=1
            const f16x8 bh0 = *(const f16x8*)(smem + BH_OFF + fr0 * 1024 + lane * 16);
            const f16x8 bl0 = *(const f16x8*)(smem + BL_OFF + fr0 * 1024 + lane * 16);
            const f16x8 bh1 = *(const f16x8*)(smem + BH_OFF + fr1 * 1024 + lane * 16);
            const f16x8 bl1 = *(const f16x8*)(smem + BL_OFF + fr1 * 1024 + lane * 16);
            #pragma unroll
            for (int t = 0; t < 2; ++t) {
                f32x4 a0 = {0.f, 0.f, 0.f, 0.f};
                f32x4 a1 = {0.f, 0.f, 0.f, 0.f};
                a0 = __builtin_amdgcn_mfma_f32_16x16x32_f16(zh[t][0], bh0, a0, 0, 0, 0);
                a1 = __builtin_amdgcn_mfma_f32_16x16x32_f16(zh[t][1], bh1, a1, 0, 0, 0);
                a0 = __builtin_amdgcn_mfma_f32_16x16x32_f16(zl[t][0], bh0, a0, 0, 0, 0);
                a1 = __builtin_amdgcn_mfma_f32_16x16x32_f16(zl[t][1], bh1, a1, 0, 0, 0);
                a0 = __builtin_amdgcn_mfma_f32_16x16x32_f16(zh[t][0], bl0, a0, 0, 0, 0);
                a1 = __builtin_amdgcn_mfma_f32_16x16x32_f16(zh[t][1], bl1, a1, 0, 0, 0);
                #pragma unroll
                for (int r = 0; r < 4; ++r)
                    PT[t][f][r] = (a0[r] + a1[r]) * PC[t][f][r] - b * PT[t][f][r];
            }
        }
        __builtin_amdgcn_s_setprio(0);
    };

    // prologue: load z for iter 0
    float4 zraw[2][4];
    #pragma unroll
    for (int t = 0; t < 2; ++t)
        #pragma unroll
        for (int s = 0; s < 2; ++s) {
            const float* p = z + (rowbase + t * 16 + lrow) * 64 + (s << 5) + (lhi << 3);
            zraw[t][2 * s]     = *(const float4*)(p);
            zraw[t][2 * s + 1] = *(const float4*)(p + 4);
        }

    for (int it = 0; it < 8; ++it) {
        // convert staged z to f16 hi/lo fragments
        #pragma unroll
        for (int t = 0; t < 2; ++t)
            #pragma unroll
            for (int s = 0; s < 2; ++s) {
                const float4 q0 = zraw[t][2 * s], q1 = zraw[t][2 * s + 1];
                const float vv[8] = {q0.x, q0.y, q0.z, q0.w, q1.x, q1.y, q1.z, q1.w};
                #pragma unroll
                for (int j = 0; j < 8; ++j) {
                    const _Float16 h = (_Float16)vv[j];
                    zh[t][s][j] = h;
                    zl[t][s][j] = (_Float16)(vv[j] - (float)h);
                }
            }
        // prefetch next iter's z (in flight across the mat loop; dead before
        // the epilogue so it does NOT extend the epilogue live set)
        if (it < 7) {
            #pragma unroll
            for (int t = 0; t < 2; ++t)
                #pragma unroll
                for (int s = 0; s < 2; ++s) {
                    const float* p = z + (rowbase + (it + 1) * 32 + t * 16 + lrow) * 64
                                       + (s << 5) + (lhi << 3);
                    zraw[t][2 * s]     = *(const float4*)(p);
                    zraw[t][2 * s + 1] = *(const float4*)(p + 4);
                }
        }

        // Legendre chain: pA = P1, pB = P2, then ping-pong; P6 ends in pB
        f32x4 pA[2][4], pB[2][4];
        // mat 0 -> pA  (P1) = a0 + a1
        __builtin_amdgcn_s_setprio(1);
        #pragma unroll
        for (int f = 0; f < 4; ++f) {
            const int fr0 = f, fr1 = 4 + f;
            const f16x8 bh0 = *(const f16x8*)(smem + BH_OFF + fr0 * 1024 + lane * 16);
            const f16x8 bl0 = *(const f16x8*)(smem + BL_OFF + fr0 * 1024 + lane * 16);
            const f16x8 bh1 = *(const f16x8*)(smem + BH_OFF + fr1 * 1024 + lane * 16);
            const f16x8 bl1 = *(const f16x8*)(smem + BL_OFF + fr1 * 1024 + lane * 16);
            #pragma unroll
            for (int t = 0; t < 2; ++t) {
                f32x4 a0 = {0.f, 0.f, 0.f, 0.f};
                f32x4 a1 = {0.f, 0.f, 0.f, 0.f};
                a0 = __builtin_amdgcn_mfma_f32_16x16x32_f16(zh[t][0], bh0, a0, 0, 0, 0);
                a1 = __builtin_amdgcn_mfma_f32_16x16x32_f16(zh[t][1], bh1, a1, 0, 0, 0);
                a0 = __builtin_amdgcn_mfma_f32_16x16x32_f16(zl[t][0], bh0, a0, 0, 0, 0);
                a1 = __builtin_amdgcn_mfma_f32_16x16x32_f16(zl[t][1], bh1, a1, 0, 0, 0);
                a0 = __builtin_amdgcn_mfma_f32_16x16x32_f16(zh[t][0], bl0, a0, 0, 0, 0);
                a1 = __builtin_amdgcn_mfma_f32_16x16x32_f16(zh[t][1], bl1, a1, 0, 0, 0);
                #pragma unroll
                for (int r = 0; r < 4; ++r)
                    pA[t][f][r] = a0[r] + a1[r];
            }
        }
        // mat 1 -> pB = W2*pA - 0.5  (P2; P0 = ones)
        #pragma unroll
        for (int f = 0; f < 4; ++f) {
            const int fr0 = 8 + f, fr1 = 12 + f;
            const f16x8 bh0 = *(const f16x8*)(smem + BH_OFF + fr0 * 1024 + lane * 16);
            const f16x8 bl0 = *(const f16x8*)(smem + BL_OFF + fr0 * 1024 + lane * 16);
            const f16x8 bh1 = *(const f16x8*)(smem + BH_OFF + fr1 * 1024 + lane * 16);
            const f16x8 bl1 = *(const f16x8*)(smem + BL_OFF + fr1 * 1024 + lane * 16);
            #pragma unroll
            for (int t = 0; t < 2; ++t) {
                f32x4 a0 = {0.f, 0.f, 0.f, 0.f};
                f32x4 a1 = {0.f, 0.f, 0.f, 0.f};
                a0 = __builtin_amdgcn_mfma_f32_16x16x32_f16(zh[t][0], bh0, a0, 0, 0, 0);
                a1 = __builtin_amdgcn_mfma_f32_16x16x32_f16(zh[t][1], bh1, a1, 0, 0, 0);
                a0 = __builtin_amdgcn_mfma_f32_16x16x32_f16(zl[t][0], bh0, a0, 0, 0, 0);
                a1 = __builtin_amdgcn_mfma_f32_16x16x32_f16(zl[t][1], bh1, a1, 0, 0, 0);
                a0 = __builtin_amdgcn_mfma_f32_16x16x32_f16(zh[t][0], bl0, a0, 0, 0, 0);
                a1 = __builtin_amdgcn_mfma_f32_16x16x32_f16(zh[t][1], bl1, a1, 0, 0, 0);
                #pragma unroll
                for (int r = 0; r < 4; ++r)
                    pB[t][f][r] = (a0[r] + a1[r]) * pA[t][f][r] - 0.5f;
            }
        }
        __builtin_amdgcn_s_setprio(0);
        leg_step(2, 2.f / 3.f, pB, pA);   // P3
        leg_step(3, 3.f / 4.f, pA, pB);   // P4
        leg_step(4, 4.f / 5.f, pB, pA);   // P5
        leg_step(5, 5.f / 6.f, pA, pB);   // P6 = pB

        // ---------------- epilogue: out = P6 @ C^T + beta -------------------
        s16x8 ch[2][2], cl[2][2];   // [s][fo]
        #pragma unroll
        for (int s = 0; s < 2; ++s)
            #pragma unroll
            for (int fo = 0; fo < 2; ++fo) {
                ch[s][fo] = *(const s16x8*)(smem + CF_OFF + ((s << 1) + fo) * 1024 + lane * 16);
                cl[s][fo] = *(const s16x8*)(smem + CF_OFF + (((2 + s) << 1) + fo) * 1024 + lane * 16);
            }
        #pragma unroll
        for (int t = 0; t < 2; ++t) {
            // transpose P6 (C/D layout) -> A-op layout via XOR-swizzled scratch
            #pragma unroll
            for (int f = 0; f < 4; ++f)
                #pragma unroll
                for (int r = 0; r < 4; ++r) {
                    const int row = lhi * 4 + r;
                    const int k   = (f << 4) + lrow;
                    const int g4  = (k >> 2) ^ row;            // group swizzle
                    scr[row * 64 + g4 * 4 + (k & 3)] = pB[t][f][r];
                }
            s16x8 p6h[2], p6l[2];
            #pragma unroll
            for (int s = 0; s < 2; ++s) {
                const int g0 = lhi * 2 + s * 8;
                const float4 q0 = *(const float4*)(scr + lrow * 64 + ((g0)     ^ lrow) * 4);
                const float4 q1 = *(const float4*)(scr + lrow * 64 + ((g0 + 1) ^ lrow) * 4);
                const float vv[8] = {q0.x, q0.y, q0.z, q0.w, q1.x, q1.y, q1.z, q1.w};
                #pragma unroll
                for (int j = 0; j < 8; ++j) {
                    const unsigned short h = f2bf(vv[j]);
                    const float hf = __builtin_bit_cast(float, (unsigned)h << 16);
                    p6h[s][j] = (short)h;
                    p6l[s][j] = (short)f2bf(vv[j] - hf);
                }
            }
            #pragma unroll
            for (int fo = 0; fo < 2; ++fo) {
                f32x4 o = {0.f, 0.f, 0.f, 0.f};
                o = __builtin_amdgcn_mfma_f32_16x16x32_bf16(p6h[0], ch[0][fo], o, 0, 0, 0);
                o = __builtin_amdgcn_mfma_f32_16x16x32_bf16(p6l[0], ch[0][fo], o, 0, 0, 0);
                o = __builtin_amdgcn_mfma_f32_16x16x32_bf16(p6h[0], cl[0][fo], o, 0, 0, 0);
                o = __builtin_amdgcn_mfma_f32_16x16x32_bf16(p6h[1], ch[1][fo], o, 0, 0, 0);
                o = __builtin_amdgcn_mfma_f32_16x16x32_bf16(p6l[1], ch[1][fo], o, 0, 0, 0);
                o = __builtin_amdgcn_mfma_f32_16x16x32_bf16(p6h[1], cl[1][fo], o, 0, 0, 0);
                const float bb = fo ? beta1 : beta0;
                const size_t r0 = rowbase + (size_t)it * 32 + t * 16 + lhi * 4;
                #pragma unroll
                for (int r = 0; r < 4; ++r)
                    out[(r0 + r) * 32 + (fo << 4) + lrow] = o[r] + bb;
            }
        }
    }
}

extern "C" void kernel_launch(void* const* d_in, const int* in_sizes, int n_in,
                              void* d_out, int out_size, void* d_ws, size_t ws_size,
                              hipStream_t stream) {
    const float* z    = (const float*)d_in[0];
    const float* T    = (const float*)d_in[1];
    const float* C    = (const float*)d_in[2];
    const float* beta = (const float*)d_in[3];
    float* out = (float*)d_out;
    (void)in_sizes; (void)n_in; (void)out_size; (void)d_ws; (void)ws_size;

    hipFuncSetAttribute((const void*)leg_mfma,
                        hipFuncAttributeMaxDynamicSharedMemorySize, SMEM_BYTES);
    leg_mfma<<<BLOCKS, THREADS, SMEM_BYTES, stream>>>(z, T, C, beta, out);
}